// Round 9
// baseline (235.166 us; speedup 1.0000x reference)
//
#include <hip/hip_runtime.h>
#include <hip/hip_fp16.h>

// ---------------------------------------------------------------- K0: init (33 blocks)
// blocks 0..31: G[64][128], 2 rows each: G[h*8+k][i] = sum_d W[(h*8+d)*128+i]*W_att[k*8+d]
// block 32: Mt[16][8] = (W_edge_att @ W_edge)^T, sumh=0, int64-probe flag.
__global__ __launch_bounds__(256) void init_kernel(
        const float* __restrict__ W, const float* __restrict__ W_edge,
        const float* __restrict__ W_edge_att, const float* __restrict__ W_att,
        const int* __restrict__ ei,
        float* __restrict__ G, float* __restrict__ Mt,
        float* __restrict__ sumh, int* __restrict__ flags) {
    int tid = threadIdx.x;
    int b = blockIdx.x;
    if (b < 32) {
        int l = b * 2 + (tid >> 7);      // 0..63
        int i = tid & 127;
        int h = l >> 3, k = l & 7;
        float acc = 0.f;
#pragma unroll
        for (int d = 0; d < 8; ++d)
            acc += W[(h * 8 + d) * 128 + i] * W_att[k * 8 + d];
        G[l * 128 + i] = acc;
    } else {
        if (tid < 128) {
            int h = tid >> 4, k = tid & 15;
            float acc = 0.f;
#pragma unroll 8
            for (int j = 0; j < 64; ++j)
                acc += W_edge_att[h * 64 + j] * W_edge[j * 16 + k];
            Mt[k * 8 + h] = acc;
        }
        if (tid < 8) sumh[tid] = 0.f;
        if (tid == 0) {
            int zc = 0;
            for (int i = 1; i < 128; i += 2) zc += (ei[i] == 0);
            flags[0] = (zc >= 60) ? 1 : 0;
        }
    }
}

// ---------------------------------------------------------------- K1: g = x @ G.T (+ g16 fp16 copy + zero S)
#define GT_ROWS 128
__global__ __launch_bounds__(256) void g_kernel(
        const float* __restrict__ x, const float* __restrict__ G,
        float* __restrict__ g, __half* __restrict__ g16,
        float* __restrict__ S, int N) {
    __shared__ float smem[13056];    // 52.2 KB: sG[64*132] | sx[128*36]; epilogue reuses as 128*68
    float* sG = smem;
    float* sx = smem + 8448;
    int tid = threadIdx.x;
    int nbase = blockIdx.x * GT_ROWS;
    for (int f4 = tid; f4 < 2048; f4 += 256) {          // stage G once
        int l = f4 >> 5, i4 = f4 & 31;
        *(float4*)&sG[l * 132 + i4 * 4] = ((const float4*)G)[f4];
    }
    int lane = tid & 63, wave = tid >> 6;
    int rg = lane >> 3;              // 0..7
    int cg = lane & 7;               // 0..7
    int rbase = wave * 32 + rg;      // block-local rows rbase + 8*r
    float acc[4][8];
#pragma unroll
    for (int r = 0; r < 4; ++r)
#pragma unroll
        for (int c = 0; c < 8; ++c) acc[r][c] = 0.f;

    for (int k0 = 0; k0 < 128; k0 += 32) {
        __syncthreads();
        for (int f4 = tid; f4 < 1024; f4 += 256) {      // stage x K-chunk
            int row = f4 >> 3, i4 = f4 & 7;
            int n = nbase + row;
            float4 v = make_float4(0.f, 0.f, 0.f, 0.f);
            if (n < N) v = *(const float4*)(x + (size_t)n * 128 + k0 + i4 * 4);
            *(float4*)&sx[row * 36 + i4 * 4] = v;
        }
        __syncthreads();
#pragma unroll
        for (int w = 0; w < 8; ++w) {
            float4 gv[8], xv[4];
#pragma unroll
            for (int c = 0; c < 8; ++c)
                gv[c] = *(const float4*)&sG[(cg + 8 * c) * 132 + k0 + w * 4];
#pragma unroll
            for (int r = 0; r < 4; ++r)
                xv[r] = *(const float4*)&sx[(rbase + 8 * r) * 36 + w * 4];
#pragma unroll
            for (int r = 0; r < 4; ++r)
#pragma unroll
                for (int c = 0; c < 8; ++c)
                    acc[r][c] += xv[r].x * gv[c].x + xv[r].y * gv[c].y
                               + xv[r].z * gv[c].z + xv[r].w * gv[c].w;
        }
    }
    // fp32 g store straight from registers
#pragma unroll
    for (int r = 0; r < 4; ++r) {
        int n = nbase + rbase + 8 * r;
        if (n < N) {
#pragma unroll
            for (int c = 0; c < 8; ++c)
                g[(size_t)n * 64 + cg + 8 * c] = acc[r][c];
        }
    }
    // transpose via LDS -> packed fp16 rows
    __syncthreads();
#pragma unroll
    for (int r = 0; r < 4; ++r)
#pragma unroll
        for (int c = 0; c < 8; ++c)
            smem[(rbase + 8 * r) * 68 + cg + 8 * c] = acc[r][c];
    __syncthreads();
    for (int u = tid; u < 1024; u += 256) {             // 128 rows x 8 uint4
        int row = u >> 3, q = u & 7;
        int n = nbase + row;
        if (n < N) {
            float4 f0 = *(const float4*)&smem[row * 68 + q * 8];
            float4 f1 = *(const float4*)&smem[row * 68 + q * 8 + 4];
            __half2 h0 = __floats2half2_rn(f0.x, f0.y);
            __half2 h1 = __floats2half2_rn(f0.z, f0.w);
            __half2 h2 = __floats2half2_rn(f1.x, f1.y);
            __half2 h3 = __floats2half2_rn(f1.z, f1.w);
            uint4 uv = make_uint4(*(unsigned*)&h0, *(unsigned*)&h1,
                                  *(unsigned*)&h2, *(unsigned*)&h3);
            ((uint4*)g16)[(size_t)n * 8 + q] = uv;
        }
    }
    for (int idx = tid; idx < GT_ROWS * 8; idx += 256) { // zero S (ws is poisoned)
        int n = nbase + (idx >> 3);
        if (n < N) S[(size_t)n * 8 + (idx & 7)] = 0.f;
    }
}

// ---------------------------------------------------------------- K2: fused edge pass
// Block stages 256 edges' attr (stride-20 LDS rows, f4-aligned, conflict-free)
// and (s,d) indices; lane = (edge x head). VMEM/lane-it: gs + gd + atomic +
// ~0.75 amortized staging (was ~8.3 -> VMEM-issue-bound fix).
#define EPB 256
__global__ __launch_bounds__(256) void edge_kernel(
        const float* __restrict__ edge_attr, const int* __restrict__ ei,
        const float* __restrict__ Mt, const __half* __restrict__ g16,
        float* __restrict__ S, float* __restrict__ sumh,
        const int* __restrict__ flags, int E) {
    __shared__ float sMt[128];        // Mt[k][h]
    __shared__ float sAttr[EPB * 20]; // 20 KB, stride 20 (f4-aligned, banks 4*(5e+q)%32)
    __shared__ int   sS[EPB], sD[EPB];
    __shared__ float wsum[4][8];
    int tid = threadIdx.x;
    if (tid < 128) sMt[tid] = Mt[tid];
    int idx64 = flags[0];
    int ebase = blockIdx.x * EPB;
    {   // stage indices: 2 VMEM per thread for the whole block
        int e = ebase + tid;
        if (idx64) {
            const long long* ei64 = (const long long*)ei;
            sS[tid] = (e < E) ? (int)ei64[e] : 0;
            sD[tid] = (e < E) ? (int)ei64[(size_t)E + e] : 0;
        } else {
            sS[tid] = (e < E) ? ei[e] : 0;
            sD[tid] = (e < E) ? ei[(size_t)E + e] : 0;
        }
    }
    for (int v = tid; v < EPB * 4; v += 256) {  // stage attr: 4 f4 per thread
        int el = v >> 2, q = v & 3;
        int e = ebase + el;
        float4 val = make_float4(0.f, 0.f, 0.f, 0.f);
        if (e < E) val = ((const float4*)edge_attr)[(size_t)e * 4 + q];
        *(float4*)&sAttr[el * 20 + q * 4] = val;
    }
    __syncthreads();

    int h = tid & 7;                  // head
    int grp = tid >> 3;               // 32 groups per block
    const uint4* g16v = (const uint4*)g16;
    int sIdx[8], dIdx[8];
#pragma unroll
    for (int it = 0; it < 8; ++it) {
        sIdx[it] = sS[it * 32 + grp];
        dIdx[it] = sD[it * 32 + grp];
    }
    uint4 gsv[2], gdv[2];
    gsv[0] = g16v[(size_t)sIdx[0] * 8 + h];
    gdv[0] = g16v[(size_t)dIdx[0] * 8 + h];
    float wacc = 0.f;
#pragma unroll
    for (int it = 0; it < 8; ++it) {
        int buf = it & 1;
        if (it + 1 < 8) {                     // depth-2 gather prefetch
            gsv[buf ^ 1] = g16v[(size_t)sIdx[it + 1] * 8 + h];
            gdv[buf ^ 1] = g16v[(size_t)dIdx[it + 1] * 8 + h];
        }
        int el = it * 32 + grp;
        float4 v0 = *(const float4*)&sAttr[el * 20];
        float4 v1 = *(const float4*)&sAttr[el * 20 + 4];
        float4 v2 = *(const float4*)&sAttr[el * 20 + 8];
        float4 v3 = *(const float4*)&sAttr[el * 20 + 12];
        float ea =
            sMt[0*8+h]*v0.x + sMt[1*8+h]*v0.y + sMt[2*8+h]*v0.z + sMt[3*8+h]*v0.w +
            sMt[4*8+h]*v1.x + sMt[5*8+h]*v1.y + sMt[6*8+h]*v1.z + sMt[7*8+h]*v1.w +
            sMt[8*8+h]*v2.x + sMt[9*8+h]*v2.y + sMt[10*8+h]*v2.z + sMt[11*8+h]*v2.w +
            sMt[12*8+h]*v3.x + sMt[13*8+h]*v3.y + sMt[14*8+h]*v3.z + sMt[15*8+h]*v3.w;
        const __half2* a2 = (const __half2*)&gsv[buf];
        const __half2* b2 = (const __half2*)&gdv[buf];
        float dot = 0.f;
#pragma unroll
        for (int j = 0; j < 4; ++j) {
            float2 fa = __half22float2(a2[j]);
            float2 fb = __half22float2(b2[j]);
            dot += fa.x * fb.x + fa.y * fb.y;
        }
        float t = dot + 8.f * ea;                  // edge_term = ea * D
        t = (t > 0.f) ? t : 0.2f * t;              // leaky_relu(0.2)
        int e = ebase + el;
        if (e < E) {
            float w = expf(t);
            unsafeAtomicAdd(S + (size_t)dIdx[it] * 8 + h, w);
            wacc += w;
        }
    }
    wacc += __shfl_xor(wacc, 8, 64);
    wacc += __shfl_xor(wacc, 16, 64);
    wacc += __shfl_xor(wacc, 32, 64);
    int wave = tid >> 6, lane = tid & 63;
    if (lane < 8) wsum[wave][lane] = wacc;
    __syncthreads();
    if (tid < 8)
        unsafeAtomicAdd(&sumh[tid], wsum[0][tid] + wsum[1][tid] + wsum[2][tid] + wsum[3][tid]);
}

// ---------------------------------------------------------------- K3: out = relu(((g .* S_broadcast) / sum_h) @ W_out.T)
__global__ __launch_bounds__(256) void out_kernel(
        const float* __restrict__ g, const float* __restrict__ S,
        const float* __restrict__ W_out, const float* __restrict__ sumh,
        float* __restrict__ out, int N) {
    __shared__ float sWo[8 * 68];
    __shared__ float sAgg[32 * 68];
    __shared__ float sSum[8];
    int tid = threadIdx.x;
    if (tid < 8) sSum[tid] = sumh[tid];
    __syncthreads();
    for (int idx = tid; idx < 512; idx += 256) {
        int k = idx >> 6, j = idx & 63;
        sWo[k * 68 + j] = W_out[idx] / sSum[j >> 3];   // fold softmax denom
    }
    int nbase = blockIdx.x * 32;
    for (int f4 = tid; f4 < 512; f4 += 256) {          // 32 rows x 16 float4
        int nl = f4 >> 4, j4 = f4 & 15;
        int n = nbase + nl;
        float4 v = make_float4(0.f, 0.f, 0.f, 0.f);
        if (n < N) {
            float sv = S[(size_t)n * 8 + (j4 >> 1)];
            float4 gv = ((const float4*)(g + (size_t)n * 64))[j4];
            v = make_float4(gv.x * sv, gv.y * sv, gv.z * sv, gv.w * sv);
        }
        *(float4*)&sAgg[nl * 68 + j4 * 4] = v;
    }
    __syncthreads();
    int nl = tid >> 3, k = tid & 7;
    int n = nbase + nl;
    float acc = 0.f;
#pragma unroll
    for (int j = 0; j < 64; j += 4) {
        float4 av = *(const float4*)&sAgg[nl * 68 + j];
        float4 wv = *(const float4*)&sWo[k * 68 + j];
        acc += av.x * wv.x + av.y * wv.y + av.z * wv.z + av.w * wv.w;
    }
    if (n < N)
        out[(size_t)n * 8 + k] = (acc > 0.f) ? acc : 0.f;
}

extern "C" void kernel_launch(void* const* d_in, const int* in_sizes, int n_in,
                              void* d_out, int out_size, void* d_ws, size_t ws_size,
                              hipStream_t stream) {
    const float* x          = (const float*)d_in[0];
    const float* edge_attr  = (const float*)d_in[1];
    const float* W          = (const float*)d_in[2];
    const float* W_edge     = (const float*)d_in[3];
    const float* W_edge_att = (const float*)d_in[4];
    const float* W_att      = (const float*)d_in[5];
    const float* W_out      = (const float*)d_in[6];
    const int*   ei         = (const int*)d_in[7];
    float* out = (float*)d_out;

    int N = in_sizes[0] / 128;   // 50000
    int E = in_sizes[1] / 16;    // 800000

    float* ws    = (float*)d_ws;
    float* G     = ws;                           // 8192
    float* Mt    = ws + 8192;                    // 128
    float* sumh  = ws + 8320;                    // 8
    int*   flags = (int*)(ws + 8328);            // 1
    float* g     = ws + 8448;                    // N*64 fp32
    float* S     = g + (size_t)N * 64;           // N*8
    __half* g16  = (__half*)(S + (size_t)N * 8); // N*64 fp16 (16B-aligned)
    // total ~21 MB of ws

    hipLaunchKernelGGL(init_kernel, dim3(33), dim3(256), 0, stream,
                       W, W_edge, W_edge_att, W_att, ei, G, Mt, sumh, flags);
    hipLaunchKernelGGL(g_kernel, dim3((N + GT_ROWS - 1) / GT_ROWS), dim3(256), 0, stream,
                       x, G, g, g16, S, N);
    hipLaunchKernelGGL(edge_kernel, dim3((E + EPB - 1) / EPB), dim3(256), 0, stream,
                       edge_attr, ei, Mt, g16, S, sumh, flags, E);
    hipLaunchKernelGGL(out_kernel, dim3((N + 31) / 32), dim3(256), 0, stream,
                       g, S, W_out, sumh, out, N);
}

// Round 10
// 223.200 us; speedup vs baseline: 1.0536x; 1.0536x over previous
//
#include <hip/hip_runtime.h>
#include <hip/hip_fp16.h>

#define GT_ROWS 128

// ---------------------------------------------------------------- K1: h_raw = x @ W^T, then per-head
// 8x8 W_att transform -> g16 (fp16, packed rows). Zeroes S. Block 0 also computes
// Mt = (W_edge_att @ W_edge)^T, the int64-probe flag, and zeroes sumh.
__global__ __launch_bounds__(256) void g_kernel(
        const float* __restrict__ x, const float* __restrict__ W,
        const float* __restrict__ W_att, const float* __restrict__ W_edge,
        const float* __restrict__ W_edge_att, const int* __restrict__ ei,
        __half* __restrict__ g16, float* __restrict__ S,
        float* __restrict__ Mt, float* __restrict__ sumh, int* __restrict__ flags,
        int N) {
    __shared__ float smem[13056];    // 52.2 KB: sW[64*132] | sx[128*36]; epilogue reuses as 128*68
    float* sW = smem;
    float* sx = smem + 8448;
    int tid = threadIdx.x;
    int nbase = blockIdx.x * GT_ROWS;

    if (blockIdx.x == 0) {           // side jobs for the edge pass
        if (tid < 128) {
            int h = tid >> 4, k = tid & 15;
            float acc = 0.f;
#pragma unroll 8
            for (int j = 0; j < 64; ++j)
                acc += W_edge_att[h * 64 + j] * W_edge[j * 16 + k];
            Mt[k * 8 + h] = acc;     // transposed: Mt[k][h]
        }
        if (tid < 8) sumh[tid] = 0.f;
        if (tid == 0) {
            int zc = 0;              // int64 edge_index: odd int32 words all zero
            for (int i = 1; i < 128; i += 2) zc += (ei[i] == 0);
            flags[0] = (zc >= 60) ? 1 : 0;
        }
    }

    for (int f4 = tid; f4 < 2048; f4 += 256) {          // stage W (same shape G had)
        int l = f4 >> 5, i4 = f4 & 31;
        *(float4*)&sW[l * 132 + i4 * 4] = ((const float4*)W)[f4];
    }
    int lane = tid & 63, wave = tid >> 6;
    int rg = lane >> 3;              // 0..7
    int cg = lane & 7;               // 0..7
    int rbase = wave * 32 + rg;      // block-local rows rbase + 8*r
    float acc[4][8];
#pragma unroll
    for (int r = 0; r < 4; ++r)
#pragma unroll
        for (int c = 0; c < 8; ++c) acc[r][c] = 0.f;

    for (int k0 = 0; k0 < 128; k0 += 32) {
        __syncthreads();
        for (int f4 = tid; f4 < 1024; f4 += 256) {      // stage x K-chunk
            int row = f4 >> 3, i4 = f4 & 7;
            int n = nbase + row;
            float4 v = make_float4(0.f, 0.f, 0.f, 0.f);
            if (n < N) v = *(const float4*)(x + (size_t)n * 128 + k0 + i4 * 4);
            *(float4*)&sx[row * 36 + i4 * 4] = v;
        }
        __syncthreads();
#pragma unroll
        for (int w = 0; w < 8; ++w) {
            float4 gv[8], xv[4];
#pragma unroll
            for (int c = 0; c < 8; ++c)
                gv[c] = *(const float4*)&sW[(cg + 8 * c) * 132 + k0 + w * 4];
#pragma unroll
            for (int r = 0; r < 4; ++r)
                xv[r] = *(const float4*)&sx[(rbase + 8 * r) * 36 + w * 4];
#pragma unroll
            for (int r = 0; r < 4; ++r)
#pragma unroll
                for (int c = 0; c < 8; ++c)
                    acc[r][c] += xv[r].x * gv[c].x + xv[r].y * gv[c].y
                               + xv[r].z * gv[c].z + xv[r].w * gv[c].w;
        }
    }
    // transpose h_raw through LDS (lane cols are stride-8), then W_att transform
    __syncthreads();
#pragma unroll
    for (int r = 0; r < 4; ++r)
#pragma unroll
        for (int c = 0; c < 8; ++c)
            smem[(rbase + 8 * r) * 68 + cg + 8 * c] = acc[r][c];
    __syncthreads();
    {
        float4 wa[16];               // W_att[8][8] in regs (acc is dead now)
#pragma unroll
        for (int q = 0; q < 16; ++q) wa[q] = ((const float4*)W_att)[q];
        int row = tid & 127;
        int n = nbase + row;
        if (n < N) {
#pragma unroll
            for (int j = 0; j < 4; ++j) {
                int q = (tid >> 7) * 4 + j;          // head
                float4 h0 = *(const float4*)&smem[row * 68 + q * 8];
                float4 h1 = *(const float4*)&smem[row * 68 + q * 8 + 4];
                float o[8];
#pragma unroll
                for (int k = 0; k < 8; ++k) {        // g[n,q,k] = <h_raw[n,q,:], W_att[k,:]>
                    float4 w0 = wa[k * 2], w1 = wa[k * 2 + 1];
                    o[k] = h0.x * w0.x + h0.y * w0.y + h0.z * w0.z + h0.w * w0.w
                         + h1.x * w1.x + h1.y * w1.y + h1.z * w1.z + h1.w * w1.w;
                }
                __half2 p0 = __floats2half2_rn(o[0], o[1]);
                __half2 p1 = __floats2half2_rn(o[2], o[3]);
                __half2 p2 = __floats2half2_rn(o[4], o[5]);
                __half2 p3 = __floats2half2_rn(o[6], o[7]);
                uint4 uv = make_uint4(*(unsigned*)&p0, *(unsigned*)&p1,
                                      *(unsigned*)&p2, *(unsigned*)&p3);
                ((uint4*)g16)[(size_t)n * 8 + q] = uv;
            }
        }
    }
    for (int idx = tid; idx < GT_ROWS * 8; idx += 256) { // zero S (ws is poisoned)
        int n = nbase + (idx >> 3);
        if (n < N) S[(size_t)n * 8 + (idx & 7)] = 0.f;
    }
}

// ---------------------------------------------------------------- K2: fused edge pass (R8 form, depth-4)
// lane h of 8-lane group: w = exp(leaky(<g_src[h],g_dst[h]> + 8*ea_h)); S[dst][h] += w.
#define EPB 256
__global__ __launch_bounds__(256) void edge_kernel(
        const float* __restrict__ edge_attr, const int* __restrict__ ei,
        const float* __restrict__ Mt, const __half* __restrict__ g16,
        float* __restrict__ S, float* __restrict__ sumh,
        const int* __restrict__ flags, int E) {
    __shared__ float sMt[128];        // Mt[k][h]
    __shared__ float wsum[4][8];
    int tid = threadIdx.x;
    if (tid < 128) sMt[tid] = Mt[tid];
    __syncthreads();
    int idx64 = flags[0];
    int h = tid & 7;                  // head
    int grp = tid >> 3;               // 32 groups per block
    int ebase = blockIdx.x * EPB;

    int sIdx[8], dIdx[8];
    if (idx64) {
        const long long* ei64 = (const long long*)ei;
#pragma unroll
        for (int it = 0; it < 8; ++it) {
            int e = ebase + it * 32 + grp;
            sIdx[it] = (e < E) ? (int)ei64[e] : 0;
            dIdx[it] = (e < E) ? (int)ei64[(size_t)E + e] : 0;
        }
    } else {
#pragma unroll
        for (int it = 0; it < 8; ++it) {
            int e = ebase + it * 32 + grp;
            sIdx[it] = (e < E) ? ei[e] : 0;
            dIdx[it] = (e < E) ? ei[(size_t)E + e] : 0;
        }
    }

    const uint4* g16v = (const uint4*)g16;
    uint4 gsv[4], gdv[4];
    float4 at[2][4];
#pragma unroll
    for (int it = 0; it < 3; ++it) {          // prime gathers (depth 4)
        gsv[it] = g16v[(size_t)sIdx[it] * 8 + h];
        gdv[it] = g16v[(size_t)dIdx[it] * 8 + h];
    }
    {
        int e = ebase + grp;
        if (e < E) {
            const float4* p = (const float4*)(edge_attr + (size_t)e * 16);
            at[0][0] = p[0]; at[0][1] = p[1]; at[0][2] = p[2]; at[0][3] = p[3];
        }
    }
    float wacc = 0.f;
#pragma unroll
    for (int it = 0; it < 8; ++it) {
        if (it + 3 < 8) {                     // gather prefetch, depth 4
            gsv[(it + 3) & 3] = g16v[(size_t)sIdx[it + 3] * 8 + h];
            gdv[(it + 3) & 3] = g16v[(size_t)dIdx[it + 3] * 8 + h];
        }
        if (it + 1 < 8) {                     // attr prefetch, depth 2
            int e2 = ebase + (it + 1) * 32 + grp;
            if (e2 < E) {
                const float4* p = (const float4*)(edge_attr + (size_t)e2 * 16);
                at[(it + 1) & 1][0] = p[0]; at[(it + 1) & 1][1] = p[1];
                at[(it + 1) & 1][2] = p[2]; at[(it + 1) & 1][3] = p[3];
            }
        }
        int e = ebase + it * 32 + grp;
        if (e < E) {
            float4 v0 = at[it & 1][0], v1 = at[it & 1][1],
                   v2 = at[it & 1][2], v3 = at[it & 1][3];
            float ea =
                sMt[0*8+h]*v0.x + sMt[1*8+h]*v0.y + sMt[2*8+h]*v0.z + sMt[3*8+h]*v0.w +
                sMt[4*8+h]*v1.x + sMt[5*8+h]*v1.y + sMt[6*8+h]*v1.z + sMt[7*8+h]*v1.w +
                sMt[8*8+h]*v2.x + sMt[9*8+h]*v2.y + sMt[10*8+h]*v2.z + sMt[11*8+h]*v2.w +
                sMt[12*8+h]*v3.x + sMt[13*8+h]*v3.y + sMt[14*8+h]*v3.z + sMt[15*8+h]*v3.w;
            const __half2* a2 = (const __half2*)&gsv[it & 3];
            const __half2* b2 = (const __half2*)&gdv[it & 3];
            float dot = 0.f;
#pragma unroll
            for (int j = 0; j < 4; ++j) {
                float2 fa = __half22float2(a2[j]);
                float2 fb = __half22float2(b2[j]);
                dot += fa.x * fb.x + fa.y * fb.y;
            }
            float t = dot + 8.f * ea;                  // edge_term = ea * D
            t = (t > 0.f) ? t : 0.2f * t;              // leaky_relu(0.2)
            float w = expf(t);
            unsafeAtomicAdd(S + (size_t)dIdx[it] * 8 + h, w);
            wacc += w;
        }
    }
    wacc += __shfl_xor(wacc, 8, 64);
    wacc += __shfl_xor(wacc, 16, 64);
    wacc += __shfl_xor(wacc, 32, 64);
    int wave = tid >> 6, lane = tid & 63;
    if (lane < 8) wsum[wave][lane] = wacc;
    __syncthreads();
    if (tid < 8)
        unsafeAtomicAdd(&sumh[tid], wsum[0][tid] + wsum[1][tid] + wsum[2][tid] + wsum[3][tid]);
}

// ---------------------------------------------------------------- K3: out = relu(((g16 .* S) / sum_h) @ W_out.T)
__global__ __launch_bounds__(256) void out_kernel(
        const __half* __restrict__ g16, const float* __restrict__ S,
        const float* __restrict__ W_out, const float* __restrict__ sumh,
        float* __restrict__ out, int N) {
    __shared__ float sWo[8 * 68];
    __shared__ float sAgg[32 * 68];
    __shared__ float sSum[8];
    int tid = threadIdx.x;
    if (tid < 8) sSum[tid] = sumh[tid];
    __syncthreads();
    for (int idx = tid; idx < 512; idx += 256) {
        int k = idx >> 6, j = idx & 63;
        sWo[k * 68 + j] = W_out[idx] / sSum[j >> 3];   // fold softmax denom
    }
    int nbase = blockIdx.x * 32;
    {   // stage agg = g16 * S: thread -> (row = tid>>3, head = tid&7)
        int row = tid >> 3, q = tid & 7;
        int n = nbase + row;
        float4 v0 = make_float4(0.f, 0.f, 0.f, 0.f), v1 = v0;
        if (n < N) {
            uint4 gv = ((const uint4*)g16)[(size_t)n * 8 + q];
            float sv = S[(size_t)n * 8 + q];
            const __half2* hp = (const __half2*)&gv;
            float2 f0 = __half22float2(hp[0]);
            float2 f1 = __half22float2(hp[1]);
            float2 f2 = __half22float2(hp[2]);
            float2 f3 = __half22float2(hp[3]);
            v0 = make_float4(f0.x * sv, f0.y * sv, f1.x * sv, f1.y * sv);
            v1 = make_float4(f2.x * sv, f2.y * sv, f3.x * sv, f3.y * sv);
        }
        *(float4*)&sAgg[row * 68 + q * 8] = v0;
        *(float4*)&sAgg[row * 68 + q * 8 + 4] = v1;
    }
    __syncthreads();
    int nl = tid >> 3, k = tid & 7;
    int n = nbase + nl;
    float acc = 0.f;
#pragma unroll
    for (int j = 0; j < 64; j += 4) {
        float4 av = *(const float4*)&sAgg[nl * 68 + j];
        float4 wv = *(const float4*)&sWo[k * 68 + j];
        acc += av.x * wv.x + av.y * wv.y + av.z * wv.z + av.w * wv.w;
    }
    if (n < N)
        out[(size_t)n * 8 + k] = (acc > 0.f) ? acc : 0.f;
}

extern "C" void kernel_launch(void* const* d_in, const int* in_sizes, int n_in,
                              void* d_out, int out_size, void* d_ws, size_t ws_size,
                              hipStream_t stream) {
    const float* x          = (const float*)d_in[0];
    const float* edge_attr  = (const float*)d_in[1];
    const float* W          = (const float*)d_in[2];
    const float* W_edge     = (const float*)d_in[3];
    const float* W_edge_att = (const float*)d_in[4];
    const float* W_att      = (const float*)d_in[5];
    const float* W_out      = (const float*)d_in[6];
    const int*   ei         = (const int*)d_in[7];
    float* out = (float*)d_out;

    int N = in_sizes[0] / 128;   // 50000
    int E = in_sizes[1] / 16;    // 800000

    float* ws    = (float*)d_ws;
    float* Mt    = ws;                           // 128
    float* sumh  = ws + 128;                     // 8
    int*   flags = (int*)(ws + 136);             // 1
    __half* g16  = (__half*)(ws + 256);          // N*64 fp16 (16B-aligned)
    float* S     = (float*)(g16 + (size_t)N * 64); // N*8 fp32
    // total ~8 MB of ws

    hipLaunchKernelGGL(g_kernel, dim3((N + GT_ROWS - 1) / GT_ROWS), dim3(256), 0, stream,
                       x, W, W_att, W_edge, W_edge_att, ei, g16, S, Mt, sumh, flags, N);
    hipLaunchKernelGGL(edge_kernel, dim3((E + EPB - 1) / EPB), dim3(256), 0, stream,
                       edge_attr, ei, Mt, g16, S, sumh, flags, E);
    hipLaunchKernelGGL(out_kernel, dim3((N + 31) / 32), dim3(256), 0, stream,
                       g16, S, W_out, sumh, out, N);
}